// Round 3
// baseline (65.981 us; speedup 1.0000x reference)
//
#include <hip/hip_runtime.h>
#include <hip/hip_bf16.h>

typedef float f32x4 __attribute__((ext_vector_type(4)));

// Pre-kernel: single block. alpha = mean(|w|) over n elems; wq = alpha * ternary(w).
__global__ __launch_bounds__(1024) void ternary_quant_kernel(
    const float* __restrict__ w, float* __restrict__ wq, int n) {
    __shared__ float red[1024];
    __shared__ float alpha_s;
    const int tid = threadIdx.x;
    float s = 0.f;
    for (int i = tid; i < n; i += 1024) s += fabsf(w[i]);
    red[tid] = s;
    __syncthreads();
    for (int off = 512; off > 0; off >>= 1) {
        if (tid < off) red[tid] += red[tid + off];
        __syncthreads();
    }
    if (tid == 0) alpha_s = red[0] / (float)n;
    __syncthreads();
    const float alpha = alpha_s;
    const float thr = 0.7f * alpha;
    for (int i = tid; i < n; i += 1024) {
        float v = w[i];
        float t = (fabsf(v) < thr) ? 0.f : (v > 0.f ? 1.f : (v < 0.f ? -1.f : 0.f));
        wq[i] = alpha * t;
    }
}

// Main conv: block = 64 l-positions x 256 f. Thread t: fg = t&63 owns f = 4*fg..4*fg+3
// (f32x4 stores), ls = t>>6 staggers l (wave-uniform -> LDS broadcast reads).
// y[b,l,f] = bias[f] + sum_k wq[k,f] * x[b, l+k-7]   (SAME pad: lo=7, hi=8)
__global__ __launch_bounds__(256) void ternary_conv1d_kernel(
    const float* __restrict__ x,   // (B, L)
    const float* __restrict__ wq,  // (16, 256)
    const float* __restrict__ bias,// (256)
    float* __restrict__ y,         // (B, L, 256)
    int L, int ltiles) {
    const int t  = threadIdx.x;
    const int fg = t & 63;                      // f32x4 group: f = 4*fg .. 4*fg+3
    const int ls = t >> 6;                      // 0..3, wave-uniform
    const int bid = blockIdx.x;
    const int lt = bid % ltiles;
    const int b  = bid / ltiles;
    const int l0 = lt * 64;

    __shared__ float xs[80];                    // xs[j] = x[b, l0-7+j], j=0..78
    if (t < 79) {
        int gl = l0 - 7 + t;
        xs[t] = (gl >= 0 && gl < L) ? x[(size_t)b * L + gl] : 0.f;
    }

    f32x4 wv[16];
#pragma unroll
    for (int k = 0; k < 16; ++k)
        wv[k] = *reinterpret_cast<const f32x4*>(wq + k * 256 + fg * 4);
    const f32x4 bv = *reinterpret_cast<const f32x4*>(bias + fg * 4);

    __syncthreads();

    // rolling 16-wide x window; for step i covers xs[ls+4i .. ls+4i+15]
    float xw[16];
#pragma unroll
    for (int j = 0; j < 16; ++j) xw[j] = xs[ls + j];

    f32x4* outp = reinterpret_cast<f32x4*>(y) + ((size_t)b * L + l0 + ls) * 64 + fg;
#pragma unroll
    for (int i = 0; i < 16; ++i) {
        f32x4 acc = bv;
#pragma unroll
        for (int k = 0; k < 16; ++k) {
            acc += wv[k] * xw[k];               // vector fma
        }
        __builtin_nontemporal_store(acc, outp);
        outp += 256;                            // next l for this thread: l += 4
        if (i < 15) {
#pragma unroll
            for (int j = 0; j < 12; ++j) xw[j] = xw[j + 4];
#pragma unroll
            for (int j = 12; j < 16; ++j) xw[j] = xs[ls + 4 * (i + 1) + j];
        }
    }
}

extern "C" void kernel_launch(void* const* d_in, const int* in_sizes, int n_in,
                              void* d_out, int out_size, void* d_ws, size_t ws_size,
                              hipStream_t stream) {
    const float* x = (const float*)d_in[0];   // (32, 8192, 1)
    const float* w = (const float*)d_in[1];   // (16, 1, 256)
    const float* b = (const float*)d_in[2];   // (256,)
    float* y = (float*)d_out;                 // (32, 8192, 256)
    float* wq = (float*)d_ws;                 // 4096 floats scratch

    const int B = 32;
    const int L = in_sizes[0] / B;            // 8192
    const int nW = in_sizes[1];               // 4096
    const int ltiles = L / 64;                // 128

    ternary_quant_kernel<<<1, 1024, 0, stream>>>(w, wq, nW);
    ternary_conv1d_kernel<<<B * ltiles, 256, 0, stream>>>(x, wq, b, y, L, ltiles);
}

// Round 4
// 51.773 us; speedup vs baseline: 1.2744x; 1.2744x over previous
//
#include <hip/hip_runtime.h>
#include <hip/hip_bf16.h>

typedef float f32x4 __attribute__((ext_vector_type(4)));

// Pre-kernel: single block. alpha = mean(|w|) over n elems; wq = alpha * ternary(w).
__global__ __launch_bounds__(1024) void ternary_quant_kernel(
    const float* __restrict__ w, float* __restrict__ wq, int n) {
    __shared__ float red[1024];
    __shared__ float alpha_s;
    const int tid = threadIdx.x;
    float s = 0.f;
    for (int i = tid; i < n; i += 1024) s += fabsf(w[i]);
    red[tid] = s;
    __syncthreads();
    for (int off = 512; off > 0; off >>= 1) {
        if (tid < off) red[tid] += red[tid + off];
        __syncthreads();
    }
    if (tid == 0) alpha_s = red[0] / (float)n;
    __syncthreads();
    const float alpha = alpha_s;
    const float thr = 0.7f * alpha;
    for (int i = tid; i < n; i += 1024) {
        float v = w[i];
        float t = (fabsf(v) < thr) ? 0.f : (v > 0.f ? 1.f : (v < 0.f ? -1.f : 0.f));
        wq[i] = alpha * t;
    }
}

// Main conv: block = 64 l-positions x 256 f. Thread t: fg = t&63 owns f = 4*fg..4*fg+3
// (f32x4 stores, plain — nt hint measured -16% in R3), ls = t>>6 staggers l
// (wave-uniform -> LDS broadcast reads).
// y[b,l,f] = bias[f] + sum_k wq[k,f] * x[b, l+k-7]   (SAME pad: lo=7, hi=8)
__global__ __launch_bounds__(256) void ternary_conv1d_kernel(
    const float* __restrict__ x,   // (B, L)
    const float* __restrict__ wq,  // (16, 256)
    const float* __restrict__ bias,// (256)
    float* __restrict__ y,         // (B, L, 256)
    int L, int ltiles) {
    const int t  = threadIdx.x;
    const int fg = t & 63;                      // f32x4 group: f = 4*fg .. 4*fg+3
    const int ls = t >> 6;                      // 0..3, wave-uniform
    const int bid = blockIdx.x;
    const int lt = bid % ltiles;
    const int b  = bid / ltiles;
    const int l0 = lt * 64;

    __shared__ float xs[80];                    // xs[j] = x[b, l0-7+j], j=0..78
    if (t < 79) {
        int gl = l0 - 7 + t;
        xs[t] = (gl >= 0 && gl < L) ? x[(size_t)b * L + gl] : 0.f;
    }

    f32x4 wv[16];
#pragma unroll
    for (int k = 0; k < 16; ++k)
        wv[k] = *reinterpret_cast<const f32x4*>(wq + k * 256 + fg * 4);
    const f32x4 bv = *reinterpret_cast<const f32x4*>(bias + fg * 4);

    __syncthreads();

    // rolling 16-wide x window; for step i covers xs[ls+4i .. ls+4i+15]
    float xw[16];
#pragma unroll
    for (int j = 0; j < 16; ++j) xw[j] = xs[ls + j];

    f32x4* outp = reinterpret_cast<f32x4*>(y) + ((size_t)b * L + l0 + ls) * 64 + fg;
#pragma unroll
    for (int i = 0; i < 16; ++i) {
        f32x4 acc = bv;
#pragma unroll
        for (int k = 0; k < 16; ++k) {
            acc += wv[k] * xw[k];               // vector fma
        }
        *outp = acc;
        outp += 256;                            // next l for this thread: l += 4
        if (i < 15) {
#pragma unroll
            for (int j = 0; j < 12; ++j) xw[j] = xw[j + 4];
#pragma unroll
            for (int j = 12; j < 16; ++j) xw[j] = xs[ls + 4 * (i + 1) + j];
        }
    }
}

extern "C" void kernel_launch(void* const* d_in, const int* in_sizes, int n_in,
                              void* d_out, int out_size, void* d_ws, size_t ws_size,
                              hipStream_t stream) {
    const float* x = (const float*)d_in[0];   // (32, 8192, 1)
    const float* w = (const float*)d_in[1];   // (16, 1, 256)
    const float* b = (const float*)d_in[2];   // (256,)
    float* y = (float*)d_out;                 // (32, 8192, 256)
    float* wq = (float*)d_ws;                 // 4096 floats scratch

    const int B = 32;
    const int L = in_sizes[0] / B;            // 8192
    const int nW = in_sizes[1];               // 4096
    const int ltiles = L / 64;                // 128

    ternary_quant_kernel<<<1, 1024, 0, stream>>>(w, wq, nW);
    ternary_conv1d_kernel<<<B * ltiles, 256, 0, stream>>>(x, wq, b, y, L, ltiles);
}

// Round 5
// 51.628 us; speedup vs baseline: 1.2780x; 1.0028x over previous
//
#include <hip/hip_runtime.h>
#include <hip/hip_bf16.h>

typedef float f32x4 __attribute__((ext_vector_type(4)));

// Fused ternary-quant + conv1d. Persistent blocks: grid = 1024 (4/CU), each
// block owns 4 consecutive 64-wide l-tiles (weights quantized once per block).
// Every block computes alpha with the SAME reduction order -> bit-identical.
// y[b,l,f] = bias[f] + sum_k wq[k,f] * x[b, l+k-7]   (SAME pad: lo=7, hi=8)
// Thread t: fg = t&63 owns f = 4*fg..4*fg+3 (f32x4 stores, plain — nt was -16%),
// ls = t>>6 staggers l (wave-uniform -> LDS broadcast reads).
__global__ __launch_bounds__(256) void ternary_conv1d_fused(
    const float* __restrict__ x,   // (B, L)
    const float* __restrict__ w,   // (16, 256) raw
    const float* __restrict__ bias,// (256)
    float* __restrict__ y,         // (B, L, 256)
    int L) {
    const int t  = threadIdx.x;
    const int fg = t & 63;
    const int ls = t >> 6;
    const int bid = blockIdx.x;
    const int b  = bid >> 5;          // 32 groups per batch
    const int g  = bid & 31;
    const int lbase = g * 256;        // 4 tiles x 64

    __shared__ float red[256];
    __shared__ float xs[80];
    __shared__ float alpha_s;

    // ---- alpha = mean(|w|), identical order in every block ----
    float s = 0.f;
#pragma unroll
    for (int j = 0; j < 16; ++j) s += fabsf(w[t + 256 * j]);
    red[t] = s;
    __syncthreads();
    for (int off = 128; off > 0; off >>= 1) {
        if (t < off) red[t] += red[t + off];
        __syncthreads();
    }
    if (t == 0) alpha_s = red[0] * (1.0f / 4096.0f);
    __syncthreads();
    const float alpha = alpha_s;
    const float thr = 0.7f * alpha;

    // ---- ternarize weights in registers ----
    f32x4 wv[16];
#pragma unroll
    for (int k = 0; k < 16; ++k) {
        f32x4 v = *reinterpret_cast<const f32x4*>(w + k * 256 + fg * 4);
        f32x4 q;
#pragma unroll
        for (int c = 0; c < 4; ++c) {
            float vc = v[c];
            float tc = (fabsf(vc) < thr) ? 0.f : (vc > 0.f ? 1.f : (vc < 0.f ? -1.f : 0.f));
            q[c] = alpha * tc;
        }
        wv[k] = q;
    }
    const f32x4 bv = *reinterpret_cast<const f32x4*>(bias + fg * 4);

    // ---- 4 tiles of 64 l-positions ----
    for (int tt = 0; tt < 4; ++tt) {
        const int l0 = lbase + tt * 64;
        __syncthreads();                 // xs reads from previous tile done
        if (t < 79) {
            int gl = l0 - 7 + t;
            xs[t] = (gl >= 0 && gl < L) ? x[(size_t)b * L + gl] : 0.f;
        }
        __syncthreads();

        float xw[16];
#pragma unroll
        for (int j = 0; j < 16; ++j) xw[j] = xs[ls + j];

        f32x4* outp = reinterpret_cast<f32x4*>(y) + ((size_t)b * L + l0 + ls) * 64 + fg;
#pragma unroll
        for (int i = 0; i < 16; ++i) {
            f32x4 acc = bv;
#pragma unroll
            for (int k = 0; k < 16; ++k) {
                acc += wv[k] * xw[k];
            }
            *outp = acc;
            outp += 256;                 // l += 4
            if (i < 15) {
#pragma unroll
                for (int j = 0; j < 12; ++j) xw[j] = xw[j + 4];
#pragma unroll
                for (int j = 12; j < 16; ++j) xw[j] = xs[ls + 4 * (i + 1) + j];
            }
        }
    }
}

extern "C" void kernel_launch(void* const* d_in, const int* in_sizes, int n_in,
                              void* d_out, int out_size, void* d_ws, size_t ws_size,
                              hipStream_t stream) {
    const float* x = (const float*)d_in[0];   // (32, 8192, 1)
    const float* w = (const float*)d_in[1];   // (16, 1, 256)
    const float* b = (const float*)d_in[2];   // (256,)
    float* y = (float*)d_out;                 // (32, 8192, 256)

    const int B = 32;
    const int L = in_sizes[0] / B;            // 8192

    ternary_conv1d_fused<<<B * 32, 256, 0, stream>>>(x, w, b, y, L);
}